// Round 1
// baseline (1306.947 us; speedup 1.0000x reference)
//
#include <hip/hip_runtime.h>
#include <hip/hip_bf16.h>

#define HH 192
#define WW 192
#define NWIN 12
#define WSZ 16
#define OWSZ 24
#define PADK 4
#define NQ1 256      // WS*WS
#define NKV1 576     // OWS*OWS
#define C2K 64
#define H2K 4
#define HD 16        // head dim
#define SCALE_F 0.25f
#define NTOK (HH*WW)

typedef __hip_bfloat16 bf16;

__device__ __forceinline__ float bf2f(bf16 v) { return __bfloat162float(v); }
__device__ __forceinline__ bf16 f2bf(float v) { return __float2bfloat16(v); }

// ---------------- LayerNorm: one wave per 128-ch row ----------------
__launch_bounds__(256)
__global__ void ln_kernel(const float* __restrict__ in, int is, int io,
                          float* __restrict__ out, int os, int oo,
                          const float* __restrict__ g, const float* __restrict__ b,
                          int M)
{
    int row = blockIdx.x * 4 + (threadIdx.x >> 6);
    if (row >= M) return;
    int lane = threadIdx.x & 63;
    const float* p = in + (size_t)row * is + io;
    float v0 = p[lane * 2], v1 = p[lane * 2 + 1];
    float s = v0 + v1, sq = v0 * v0 + v1 * v1;
#pragma unroll
    for (int o = 32; o > 0; o >>= 1) { s += __shfl_xor(s, o); sq += __shfl_xor(sq, o); }
    float mu  = s * 0.0078125f;
    float var = sq * 0.0078125f - mu * mu;
    float inv = 1.0f / sqrtf(var + 1e-5f);
    float* q = out + (size_t)row * os + oo;
    q[lane * 2]     = (v0 - mu) * inv * g[lane * 2]     + b[lane * 2];
    q[lane * 2 + 1] = (v1 - mu) * inv * g[lane * 2 + 1] + b[lane * 2 + 1];
}

// ---------------- bias transpose: biasT[h][n][q] = rpb1[rpi[q,n]][h] ----------------
__global__ void bias1_kernel(const float* __restrict__ rpb1, const int* __restrict__ rpi,
                             float* __restrict__ biasT)
{
    int idx = blockIdx.x * 256 + threadIdx.x;
    if (idx >= H2K * NKV1 * NQ1) return;
    int q = idx & 255;
    int n = (idx >> 8) % NKV1;
    int h = idx / (NKV1 * NQ1);
    biasT[idx] = rpb1[rpi[q * NKV1 + n] * H2K + h];
}

// ---------------- attn1: xa (256 q) attends to xb_p (576 kv), per (win, head) ----------------
__launch_bounds__(256)
__global__ void attn1_kernel(const float* __restrict__ lnx,
                             const float* __restrict__ q1_w,
                             const float* __restrict__ kv1_w,
                             const float* __restrict__ biasT,
                             float* __restrict__ xcat)
{
    __shared__ bf16 Ks[NKV1][HD];
    __shared__ bf16 Vs[NKV1][HD];
    __shared__ float q1s[C2K][HD];
    __shared__ float wKs[C2K][HD];
    __shared__ float wVs[C2K][HD];

    const int win = blockIdx.x, h = blockIdx.y;
    const int wi = win / NWIN, wj = win % NWIN;
    const int tid = threadIdx.x;

    for (int i = tid; i < C2K * HD; i += 256) {
        int c = i / HD, d = i % HD;
        q1s[c][d] = q1_w[c * C2K + h * HD + d];
        wKs[c][d] = kv1_w[c * (2 * C2K) + h * HD + d];
        wVs[c][d] = kv1_w[c * (2 * C2K) + C2K + h * HD + d];
    }
    __syncthreads();

    for (int p = tid; p < NKV1; p += 256) {
        int pr = p / OWSZ, pc = p % OWSZ;
        int gr = wi * WSZ - PADK + pr, gc = wj * WSZ - PADK + pc;
        float aK[HD], aV[HD];
#pragma unroll
        for (int d = 0; d < HD; d++) { aK[d] = 0.f; aV[d] = 0.f; }
        if (gr >= 0 && gr < HH && gc >= 0 && gc < WW) {
            const float* src = lnx + ((size_t)(gr * WW + gc)) * 128 + C2K;
            for (int c = 0; c < C2K; c++) {
                float x = src[c];
#pragma unroll
                for (int d = 0; d < HD; d++) { aK[d] += x * wKs[c][d]; aV[d] += x * wVs[c][d]; }
            }
        }
#pragma unroll
        for (int d = 0; d < HD; d++) { Ks[p][d] = f2bf(aK[d]); Vs[p][d] = f2bf(aV[d]); }
    }
    __syncthreads();

    const int q = tid;
    const int pix = (wi * WSZ + q / WSZ) * WW + wj * WSZ + (q % WSZ);
    const float* xaq = lnx + (size_t)pix * 128;
    float qv[HD];
#pragma unroll
    for (int d = 0; d < HD; d++) qv[d] = 0.f;
    for (int c = 0; c < C2K; c++) {
        float x = xaq[c];
#pragma unroll
        for (int d = 0; d < HD; d++) qv[d] += x * q1s[c][d];
    }
#pragma unroll
    for (int d = 0; d < HD; d++) qv[d] *= SCALE_F;

    const float* bT = biasT + ((size_t)h * NKV1) * NQ1 + q;
    float m = -1e30f, l = 0.f, acc[HD];
#pragma unroll
    for (int d = 0; d < HD; d++) acc[d] = 0.f;
    for (int n = 0; n < NKV1; n++) {
        float s = bT[(size_t)n * NQ1];
#pragma unroll
        for (int d = 0; d < HD; d++) s += qv[d] * bf2f(Ks[n][d]);
        float mn = fmaxf(m, s);
        float e = __expf(s - mn), f = __expf(m - mn);
        l = l * f + e;
#pragma unroll
        for (int d = 0; d < HD; d++) acc[d] = acc[d] * f + e * bf2f(Vs[n][d]);
        m = mn;
    }
    float rl = 1.f / l;
    float* op = xcat + (size_t)pix * 128 + h * HD;
    const float* resp = xaq + h * HD;
#pragma unroll
    for (int d = 0; d < HD; d++) op[d] = acc[d] * rl + resp[d];
}

// ---------------- attn2: xb_p (576 q) attends to xa (256 kv), per (win, head) ----------------
__launch_bounds__(576)
__global__ void attn2_kernel(const float* __restrict__ lnx,
                             const float* __restrict__ q2_w,
                             const float* __restrict__ kv2_w,
                             const float* __restrict__ rpb2,
                             const int* __restrict__ rpi,
                             float* __restrict__ bb)
{
    __shared__ bf16 xas[NQ1][C2K];
    __shared__ bf16 Ks[NQ1][HD];
    __shared__ bf16 Vs[NQ1][HD];
    __shared__ float q2s[C2K][HD];
    __shared__ float wKs[C2K][HD];
    __shared__ float wVs[C2K][HD];

    const int win = blockIdx.x, h = blockIdx.y;
    const int wi = win / NWIN, wj = win % NWIN;
    const int tid = threadIdx.x;

    for (int i = tid; i < C2K * HD; i += 576) {
        int c = i / HD, d = i % HD;
        q2s[c][d] = q2_w[c * C2K + h * HD + d];
        wKs[c][d] = kv2_w[c * (2 * C2K) + h * HD + d];
        wVs[c][d] = kv2_w[c * (2 * C2K) + C2K + h * HD + d];
    }
    for (int i = tid; i < NQ1 * C2K; i += 576) {
        int t = i / C2K, c = i % C2K;
        int pix = (wi * WSZ + t / WSZ) * WW + wj * WSZ + (t % WSZ);
        xas[t][c] = f2bf(lnx[(size_t)pix * 128 + c]);
    }
    __syncthreads();

    for (int p = tid; p < NQ1; p += 576) {
        float aK[HD], aV[HD];
#pragma unroll
        for (int d = 0; d < HD; d++) { aK[d] = 0.f; aV[d] = 0.f; }
        for (int c = 0; c < C2K; c++) {
            float x = bf2f(xas[p][c]);
#pragma unroll
            for (int d = 0; d < HD; d++) { aK[d] += x * wKs[c][d]; aV[d] += x * wVs[c][d]; }
        }
#pragma unroll
        for (int d = 0; d < HD; d++) { Ks[p][d] = f2bf(aK[d]); Vs[p][d] = f2bf(aV[d]); }
    }
    __syncthreads();

    const int q = tid;  // 0..575
    int pr = q / OWSZ, pc = q % OWSZ;
    int gr = wi * WSZ - PADK + pr, gc = wj * WSZ - PADK + pc;
    bool inb = (gr >= 0 && gr < HH && gc >= 0 && gc < WW);
    const float* xbq = lnx + ((size_t)((inb ? gr : 0) * WW + (inb ? gc : 0))) * 128 + C2K;
    float qv[HD];
#pragma unroll
    for (int d = 0; d < HD; d++) qv[d] = 0.f;
    if (inb) {
        for (int c = 0; c < C2K; c++) {
            float x = xbq[c];
#pragma unroll
            for (int d = 0; d < HD; d++) qv[d] += x * q2s[c][d];
        }
    }
#pragma unroll
    for (int d = 0; d < HD; d++) qv[d] *= SCALE_F;

    float m = -1e30f, l = 0.f, acc[HD];
#pragma unroll
    for (int d = 0; d < HD; d++) acc[d] = 0.f;
    for (int k = 0; k < NQ1; k++) {
        float s = rpb2[rpi[k * NKV1 + q] * H2K + h];
#pragma unroll
        for (int d = 0; d < HD; d++) s += qv[d] * bf2f(Ks[k][d]);
        float mn = fmaxf(m, s);
        float e = __expf(s - mn), f = __expf(m - mn);
        l = l * f + e;
#pragma unroll
        for (int d = 0; d < HD; d++) acc[d] = acc[d] * f + e * bf2f(Vs[k][d]);
        m = mn;
    }
    float rl = 1.f / l;
    float* op = bb + ((size_t)win * NKV1 + q) * C2K + h * HD;
#pragma unroll
    for (int d = 0; d < HD; d++) op[d] = acc[d] * rl + (inb ? xbq[h * HD + d] : 0.f);
}

// ---------------- fold (gather form, no atomics) ----------------
__global__ void fold_kernel(const float* __restrict__ bb, float* __restrict__ folded)
{
    int idx = blockIdx.x * 256 + threadIdx.x;
    if (idx >= 200 * 200 * 64) return;
    int c = idx & 63;
    int j = (idx >> 6) % 200;
    int i = idx / (64 * 200);
    int ilo = (i > 23) ? ((i - 8) >> 4) : 0;
    int ihi = min(11, i >> 4);
    int jlo = (j > 23) ? ((j - 8) >> 4) : 0;
    int jhi = min(11, j >> 4);
    float s = 0.f;
    for (int wi = ilo; wi <= ihi; wi++)
        for (int wj = jlo; wj <= jhi; wj++) {
            int p = (i - wi * 16) * OWSZ + (j - wj * 16);
            s += bb[((size_t)(wi * NWIN + wj) * NKV1 + p) * C2K + c];
        }
    folded[idx] = s;
}

// ---------------- bicubic resize 200->192 (both dims), writes xcat ch 64..127 ----------------
__device__ __forceinline__ float cubicw(float x)
{
    float ax = fabsf(x);
    const float A = -0.75f;
    if (ax <= 1.f) return ((A + 2.f) * ax - (A + 3.f)) * ax * ax + 1.f;
    if (ax < 2.f)  return A * (ax * (ax * (ax - 5.f) + 8.f) - 4.f);
    return 0.f;
}

__global__ void resize_kernel(const float* __restrict__ folded, float* __restrict__ xcat)
{
    int idx = blockIdx.x * 256 + threadIdx.x;
    if (idx >= HH * WW * C2K) return;
    int c = idx & 63;
    int p = (idx >> 6) % WW;
    int o = idx / (C2K * WW);
    const float ratio = 200.f / 192.f;
    float sr = (o + 0.5f) * ratio - 0.5f;
    float sc = (p + 0.5f) * ratio - 0.5f;
    int fr = (int)floorf(sr), fcc = (int)floorf(sc);
    float wc[4]; int ic[4];
#pragma unroll
    for (int u = 0; u < 4; u++) {
        int jj = fcc - 1 + u;
        wc[u] = cubicw(sc - (float)jj);
        ic[u] = min(max(jj, 0), 199);
    }
    float acc = 0.f;
#pragma unroll
    for (int t = 0; t < 4; t++) {
        int ii = fr - 1 + t;
        float wr = cubicw(sr - (float)ii);
        int ir = min(max(ii, 0), 199);
        const float* rowp = folded + ((size_t)ir * 200) * 64 + c;
        float rs = 0.f;
#pragma unroll
        for (int u = 0; u < 4; u++) rs += wc[u] * rowp[(size_t)ic[u] * 64];
        acc += wr * rs;
    }
    xcat[(size_t)(o * WW + p) * 128 + C2K + c] = acc;
}

// ---------------- generic GEMM: C = (A1 [*A2]) @ B + bias [+ R], K = 128 ----------------
__launch_bounds__(256)
__global__ void gemm_kernel(const float* __restrict__ A1, int a1s,
                            const float* __restrict__ A2, int a2s,
                            const float* __restrict__ B, int N,
                            const float* __restrict__ bias,
                            const float* __restrict__ R, int rs,
                            float* __restrict__ C, int cs)
{
    __shared__ float As[64][128];
    __shared__ bf16 Bs[128][128];
    int row0 = blockIdx.x * 64;
    int tid = threadIdx.x;
    for (int i = tid; i < 64 * 128; i += 256) {
        int r = i >> 7, k = i & 127;
        float v = A1[(size_t)(row0 + r) * a1s + k];
        if (A2) v *= A2[(size_t)(row0 + r) * a2s + k];
        As[r][k] = v;
    }
    for (int n0 = 0; n0 < N; n0 += 128) {
        __syncthreads();
        for (int i = tid; i < 128 * 128; i += 256) {
            int k = i >> 7, nn = i & 127;
            Bs[k][nn] = f2bf(B[(size_t)k * N + n0 + nn]);
        }
        __syncthreads();
        for (int e = tid; e < 64 * 128; e += 256) {
            int r = e >> 7, nn = e & 127;
            float acc = 0.f;
            for (int k = 0; k < 128; k++) acc += As[r][k] * bf2f(Bs[k][nn]);
            acc += bias[n0 + nn];
            size_t orow = (size_t)(row0 + r);
            if (R) acc += R[orow * rs + n0 + nn];
            C[orow * cs + n0 + nn] = acc;
        }
    }
}

// ---------------- depthwise 3x3 conv ----------------
__global__ void dwconv_kernel(const float* __restrict__ x2n,  // h1 + 128, stride 256
                              const float* __restrict__ conv_w,
                              const float* __restrict__ conv_b,
                              float* __restrict__ x2c)
{
    int idx = blockIdx.x * 256 + threadIdx.x;
    if (idx >= NTOK * 128) return;
    int ch = idx & 127, t = idx >> 7;
    int i = t / WW, j = t % WW;
    float acc = conv_b[ch];
#pragma unroll
    for (int a = 0; a < 3; a++) {
        int ii = i + a - 1;
        if (ii < 0 || ii >= HH) continue;
#pragma unroll
        for (int b = 0; b < 3; b++) {
            int jj = j + b - 1;
            if (jj < 0 || jj >= WW) continue;
            acc += conv_w[ch * 9 + a * 3 + b] * x2n[(size_t)(ii * WW + jj) * 256 + ch];
        }
    }
    x2c[(size_t)t * 128 + ch] = acc;
}

extern "C" void kernel_launch(void* const* d_in, const int* in_sizes, int n_in,
                              void* d_out, int out_size, void* d_ws, size_t ws_size,
                              hipStream_t stream)
{
    (void)in_sizes; (void)n_in; (void)out_size; (void)ws_size;
    const float* x_tkn  = (const float*)d_in[0];
    const float* ln1_w  = (const float*)d_in[1];
    const float* ln1_b  = (const float*)d_in[2];
    const float* q1_w   = (const float*)d_in[3];
    const float* kv1_w  = (const float*)d_in[4];
    const float* rpb1   = (const float*)d_in[5];
    const float* q2_w   = (const float*)d_in[6];
    const float* kv2_w  = (const float*)d_in[7];
    const float* rpb2   = (const float*)d_in[8];
    const float* proj_w = (const float*)d_in[9];
    const float* proj_b = (const float*)d_in[10];
    const float* ln2_w  = (const float*)d_in[11];
    const float* ln2_b  = (const float*)d_in[12];
    const float* fc1_w  = (const float*)d_in[13];
    const float* fc1_b  = (const float*)d_in[14];
    const float* sgn_w  = (const float*)d_in[15];
    const float* sgn_b  = (const float*)d_in[16];
    const float* conv_w = (const float*)d_in[17];
    const float* conv_b = (const float*)d_in[18];
    const float* fc2_w  = (const float*)d_in[19];
    const float* fc2_b  = (const float*)d_in[20];
    const int*   rpi    = (const int*)d_in[21];

    float* ws = (float*)d_ws;
    float* lnx   = ws;               // 4,718,592  (ln_x; later x_buf)
    float* xcat  = ws + 4718592;     // 4,718,592  (x_cat; later x2c)
    float* bbuf  = ws + 9437184;     // 5,308,416  (bb; later y)
    float* foldp = ws + 14745600;    // 2,560,000  (folded)
    float* h1    = ws + 17305600;    // 9,437,184  (biasT1 early; h1 late)
    float* out   = (float*)d_out;

    // 1. LN1
    ln_kernel<<<NTOK / 4, 256, 0, stream>>>(x_tkn, 128, 0, lnx, 128, 0, ln1_w, ln1_b, NTOK);
    // 2. bias transpose for attn1
    bias1_kernel<<<(H2K * NKV1 * NQ1) / 256, 256, 0, stream>>>(rpb1, rpi, h1);
    // 3. attn1 -> xcat[:, 0:64] (+xa residual)
    attn1_kernel<<<dim3(144, 4), 256, 0, stream>>>(lnx, q1_w, kv1_w, h1, xcat);
    // 4. attn2 -> bb (+xb_p residual)
    attn2_kernel<<<dim3(144, 4), 576, 0, stream>>>(lnx, q2_w, kv2_w, rpb2, rpi, bbuf);
    // 5. fold bb -> folded (200x200x64)
    fold_kernel<<<(200 * 200 * 64) / 256, 256, 0, stream>>>(bbuf, foldp);
    // 6. bicubic resize -> xcat[:, 64:128]
    resize_kernel<<<(HH * WW * C2K) / 256, 256, 0, stream>>>(foldp, xcat);
    // 7. proj: x_buf = xcat @ proj_w + proj_b + x_tkn   (x_buf aliases lnx)
    gemm_kernel<<<NTOK / 64, 256, 0, stream>>>(xcat, 128, nullptr, 0, proj_w, 128, proj_b,
                                               x_tkn, 128, lnx, 128);
    // 8. LN2: y = LN(x_buf)   (y aliases bbuf)
    ln_kernel<<<NTOK / 4, 256, 0, stream>>>(lnx, 128, 0, bbuf, 128, 0, ln2_w, ln2_b, NTOK);
    // 9. fc1: h1 = y @ fc1_w + fc1_b  (N=256)
    gemm_kernel<<<NTOK / 64, 256, 0, stream>>>(bbuf, 128, nullptr, 0, fc1_w, 256, fc1_b,
                                               nullptr, 0, h1, 256);
    // 10. sgn LN on x2 half of h1 (in place)
    ln_kernel<<<NTOK / 4, 256, 0, stream>>>(h1, 256, 128, h1, 256, 128, sgn_w, sgn_b, NTOK);
    // 11. depthwise conv: x2c = dwconv(x2n)   (x2c aliases xcat)
    dwconv_kernel<<<(NTOK * 128) / 256, 256, 0, stream>>>(h1 + 128, conv_w, conv_b, xcat);
    // 12. fc2: out = (x1 * x2c) @ fc2_w + fc2_b + x_buf
    gemm_kernel<<<NTOK / 64, 256, 0, stream>>>(h1, 256, xcat, 128, fc2_w, 128, fc2_b,
                                               lnx, 128, out, 128);
}

// Round 3
// 813.258 us; speedup vs baseline: 1.6071x; 1.6071x over previous
//
#include <hip/hip_runtime.h>
#include <hip/hip_bf16.h>

#define HH 192
#define WW 192
#define NWIN 12
#define WSZ 16
#define OWSZ 24
#define PADK 4
#define NQ1 256      // WS*WS
#define NKV1 576     // OWS*OWS
#define C2K 64
#define H2K 4
#define HD 16        // head dim
#define SCALE_F 0.25f
#define NTOK (HH*WW)
#define KP1 192      // keys per staging pass in attn1

typedef __hip_bfloat16 bf16;

// acc[0..15] += s * w[0..15]  (w 16B-aligned)
__device__ __forceinline__ void axpy16(float* acc, float s, const float* w)
{
    const float4* wp = (const float4*)w;
    float4 w0 = wp[0], w1 = wp[1], w2 = wp[2], w3 = wp[3];
    acc[0]  += s * w0.x; acc[1]  += s * w0.y; acc[2]  += s * w0.z; acc[3]  += s * w0.w;
    acc[4]  += s * w1.x; acc[5]  += s * w1.y; acc[6]  += s * w1.z; acc[7]  += s * w1.w;
    acc[8]  += s * w2.x; acc[9]  += s * w2.y; acc[10] += s * w2.z; acc[11] += s * w2.w;
    acc[12] += s * w3.x; acc[13] += s * w3.y; acc[14] += s * w3.z; acc[15] += s * w3.w;
}

// returns dot(q[0..15], k[0..15])
__device__ __forceinline__ float dot16(const float* q, const float* k)
{
    const float4* kp = (const float4*)k;
    float4 k0 = kp[0], k1 = kp[1], k2 = kp[2], k3 = kp[3];
    return q[0]*k0.x + q[1]*k0.y + q[2]*k0.z + q[3]*k0.w
         + q[4]*k1.x + q[5]*k1.y + q[6]*k1.z + q[7]*k1.w
         + q[8]*k2.x + q[9]*k2.y + q[10]*k2.z + q[11]*k2.w
         + q[12]*k3.x + q[13]*k3.y + q[14]*k3.z + q[15]*k3.w;
}

// ---------------- LayerNorm: one wave per 128-ch row ----------------
__launch_bounds__(256)
__global__ void ln_kernel(const float* __restrict__ in, int is, int io,
                          float* __restrict__ out, int os, int oo,
                          const float* __restrict__ g, const float* __restrict__ b,
                          int M)
{
    int row = blockIdx.x * 4 + (threadIdx.x >> 6);
    if (row >= M) return;
    int lane = threadIdx.x & 63;
    const float* p = in + (size_t)row * is + io;
    float v0 = p[lane * 2], v1 = p[lane * 2 + 1];
    float s = v0 + v1, sq = v0 * v0 + v1 * v1;
#pragma unroll
    for (int o = 32; o > 0; o >>= 1) { s += __shfl_xor(s, o); sq += __shfl_xor(sq, o); }
    float mu  = s * 0.0078125f;
    float var = sq * 0.0078125f - mu * mu;
    float inv = 1.0f / sqrtf(var + 1e-5f);
    float* q = out + (size_t)row * os + oo;
    q[lane * 2]     = (v0 - mu) * inv * g[lane * 2]     + b[lane * 2];
    q[lane * 2 + 1] = (v1 - mu) * inv * g[lane * 2 + 1] + b[lane * 2 + 1];
}

// ---------------- bias transposes ----------------
// bias1T[h][n][q] = rpb1[rpi[q*576+n]*4+h]   (attn1: q fastest -> coalesced)
__global__ void bias1_kernel(const float* __restrict__ rpb1, const int* __restrict__ rpi,
                             float* __restrict__ biasT)
{
    int idx = blockIdx.x * 256 + threadIdx.x;
    if (idx >= H2K * NKV1 * NQ1) return;
    int q = idx & 255;
    int n = (idx >> 8) % NKV1;
    int h = idx / (NKV1 * NQ1);
    biasT[idx] = rpb1[rpi[q * NKV1 + n] * H2K + h];
}

// bias2T[h][k][q] = rpb2[rpi[k*576+q]*4+h]   (attn2: q fastest -> coalesced)
__global__ void bias2_kernel(const float* __restrict__ rpb2, const int* __restrict__ rpi,
                             float* __restrict__ biasT)
{
    int idx = blockIdx.x * 256 + threadIdx.x;
    if (idx >= H2K * NQ1 * NKV1) return;
    int q = idx % NKV1;
    int k = (idx / NKV1) % NQ1;
    int h = idx / (NKV1 * NQ1);
    biasT[idx] = rpb2[rpi[k * NKV1 + q] * H2K + h];
}

// ---------------- attn1: xa (256 q) attends to xb_p (576 kv), per (win, head) ----------------
__launch_bounds__(256)
__global__ void attn1_kernel(const float* __restrict__ lnx,
                             const float* __restrict__ q1_w,
                             const float* __restrict__ kv1_w,
                             const float* __restrict__ biasT,
                             float* __restrict__ xcat)
{
    __shared__ __align__(16) float q1s[C2K][HD];
    __shared__ __align__(16) float wKs[C2K][HD];
    __shared__ __align__(16) float wVs[C2K][HD];
    __shared__ __align__(16) float Ks[KP1][20];
    __shared__ __align__(16) float Vs[KP1][20];

    const int win = blockIdx.x, h = blockIdx.y;
    const int wi = win / NWIN, wj = win % NWIN;
    const int tid = threadIdx.x;

    for (int i = tid; i < C2K * HD; i += 256) {
        int c = i >> 4, d = i & 15;
        q1s[c][d] = q1_w[c * C2K + h * HD + d];
        wKs[c][d] = kv1_w[c * (2 * C2K) + h * HD + d];
        wVs[c][d] = kv1_w[c * (2 * C2K) + C2K + h * HD + d];
    }
    __syncthreads();

    // query projection (q = tid)
    const int q = tid;
    const int pix = (wi * WSZ + (q >> 4)) * WW + wj * WSZ + (q & 15);
    float qv[16];
#pragma unroll
    for (int d = 0; d < 16; d++) qv[d] = 0.f;
    {
        const float4* xp = (const float4*)(lnx + (size_t)pix * 128);
#pragma unroll 4
        for (int c4 = 0; c4 < 16; c4++) {
            float4 x4 = xp[c4];
            axpy16(qv, x4.x, q1s[c4 * 4 + 0]);
            axpy16(qv, x4.y, q1s[c4 * 4 + 1]);
            axpy16(qv, x4.z, q1s[c4 * 4 + 2]);
            axpy16(qv, x4.w, q1s[c4 * 4 + 3]);
        }
#pragma unroll
        for (int d = 0; d < 16; d++) qv[d] *= SCALE_F;
    }

    float m = -1e30f, l = 0.f, acc[16];
#pragma unroll
    for (int d = 0; d < 16; d++) acc[d] = 0.f;
    const float* bp = biasT + ((size_t)h * NKV1) * NQ1 + q;

    for (int pass = 0; pass < 3; pass++) {
        __syncthreads();
        if (tid < KP1) {
            int n = pass * KP1 + tid;
            int gr = wi * WSZ - PADK + n / OWSZ, gc = wj * WSZ - PADK + n % OWSZ;
            float aK[16], aV[16];
#pragma unroll
            for (int d = 0; d < 16; d++) { aK[d] = 0.f; aV[d] = 0.f; }
            if (gr >= 0 && gr < HH && gc >= 0 && gc < WW) {
                const float4* src = (const float4*)(lnx + (size_t)(gr * WW + gc) * 128 + C2K);
#pragma unroll 2
                for (int c4 = 0; c4 < 16; c4++) {
                    float4 x4 = src[c4];
                    axpy16(aK, x4.x, wKs[c4 * 4 + 0]); axpy16(aV, x4.x, wVs[c4 * 4 + 0]);
                    axpy16(aK, x4.y, wKs[c4 * 4 + 1]); axpy16(aV, x4.y, wVs[c4 * 4 + 1]);
                    axpy16(aK, x4.z, wKs[c4 * 4 + 2]); axpy16(aV, x4.z, wVs[c4 * 4 + 2]);
                    axpy16(aK, x4.w, wKs[c4 * 4 + 3]); axpy16(aV, x4.w, wVs[c4 * 4 + 3]);
                }
            }
            float4* kd = (float4*)&Ks[tid][0];
            kd[0] = make_float4(aK[0], aK[1], aK[2], aK[3]);
            kd[1] = make_float4(aK[4], aK[5], aK[6], aK[7]);
            kd[2] = make_float4(aK[8], aK[9], aK[10], aK[11]);
            kd[3] = make_float4(aK[12], aK[13], aK[14], aK[15]);
            float4* vd = (float4*)&Vs[tid][0];
            vd[0] = make_float4(aV[0], aV[1], aV[2], aV[3]);
            vd[1] = make_float4(aV[4], aV[5], aV[6], aV[7]);
            vd[2] = make_float4(aV[8], aV[9], aV[10], aV[11]);
            vd[3] = make_float4(aV[12], aV[13], aV[14], aV[15]);
        }
        __syncthreads();

        const float* bpp = bp + (size_t)(pass * KP1) * NQ1;
        for (int n0 = 0; n0 < KP1; n0 += 8) {
            float s[8];
#pragma unroll
            for (int j = 0; j < 8; j++) s[j] = bpp[(size_t)(n0 + j) * NQ1];
#pragma unroll
            for (int j = 0; j < 8; j++) s[j] += dot16(qv, Ks[n0 + j]);
            float cm = fmaxf(fmaxf(fmaxf(s[0], s[1]), fmaxf(s[2], s[3])),
                             fmaxf(fmaxf(s[4], s[5]), fmaxf(s[6], s[7])));
            float mn = fmaxf(m, cm);
            float corr = __expf(m - mn);
            m = mn;
            l *= corr;
#pragma unroll
            for (int d = 0; d < 16; d++) acc[d] *= corr;
#pragma unroll
            for (int j = 0; j < 8; j++) {
                float e = __expf(s[j] - mn);
                l += e;
                axpy16(acc, e, Vs[n0 + j]);
            }
        }
    }

    float rl = 1.f / l;
    float* op = xcat + (size_t)pix * 128 + h * HD;
    const float* resp = lnx + (size_t)pix * 128 + h * HD;
#pragma unroll
    for (int d = 0; d < 16; d++) op[d] = acc[d] * rl + resp[d];
}

// ---------------- attn2: xb_p (576 q) attends to xa (256 kv), per (win, head) ----------------
__launch_bounds__(576)
__global__ void attn2_kernel(const float* __restrict__ lnx,
                             const float* __restrict__ q2_w,
                             const float* __restrict__ kv2_w,
                             const float* __restrict__ biasT,
                             float* __restrict__ bb)
{
    __shared__ __align__(16) float q2s[C2K][HD];
    __shared__ __align__(16) float wKs[C2K][HD];
    __shared__ __align__(16) float wVs[C2K][HD];
    __shared__ __align__(16) float Ks[NQ1][20];
    __shared__ __align__(16) float Vs[NQ1][20];

    const int win = blockIdx.x, h = blockIdx.y;
    const int wi = win / NWIN, wj = win % NWIN;
    const int tid = threadIdx.x;

    for (int i = tid; i < C2K * HD; i += 576) {
        int c = i >> 4, d = i & 15;
        q2s[c][d] = q2_w[c * C2K + h * HD + d];
        wKs[c][d] = kv2_w[c * (2 * C2K) + h * HD + d];
        wVs[c][d] = kv2_w[c * (2 * C2K) + C2K + h * HD + d];
    }
    __syncthreads();

    // K/V projection from xa (first 64 channels of the window's tokens)
    if (tid < NQ1) {
        int p = tid;
        int pix = (wi * WSZ + (p >> 4)) * WW + wj * WSZ + (p & 15);
        const float4* src = (const float4*)(lnx + (size_t)pix * 128);
        float aK[16], aV[16];
#pragma unroll
        for (int d = 0; d < 16; d++) { aK[d] = 0.f; aV[d] = 0.f; }
#pragma unroll 2
        for (int c4 = 0; c4 < 16; c4++) {
            float4 x4 = src[c4];
            axpy16(aK, x4.x, wKs[c4 * 4 + 0]); axpy16(aV, x4.x, wVs[c4 * 4 + 0]);
            axpy16(aK, x4.y, wKs[c4 * 4 + 1]); axpy16(aV, x4.y, wVs[c4 * 4 + 1]);
            axpy16(aK, x4.z, wKs[c4 * 4 + 2]); axpy16(aV, x4.z, wVs[c4 * 4 + 2]);
            axpy16(aK, x4.w, wKs[c4 * 4 + 3]); axpy16(aV, x4.w, wVs[c4 * 4 + 3]);
        }
        float4* kd = (float4*)&Ks[p][0];
        kd[0] = make_float4(aK[0], aK[1], aK[2], aK[3]);
        kd[1] = make_float4(aK[4], aK[5], aK[6], aK[7]);
        kd[2] = make_float4(aK[8], aK[9], aK[10], aK[11]);
        kd[3] = make_float4(aK[12], aK[13], aK[14], aK[15]);
        float4* vd = (float4*)&Vs[p][0];
        vd[0] = make_float4(aV[0], aV[1], aV[2], aV[3]);
        vd[1] = make_float4(aV[4], aV[5], aV[6], aV[7]);
        vd[2] = make_float4(aV[8], aV[9], aV[10], aV[11]);
        vd[3] = make_float4(aV[12], aV[13], aV[14], aV[15]);
    }

    // query projection (q = tid over 576 patch positions)
    const int q = tid;
    int pr = q / OWSZ, pc = q % OWSZ;
    int gr = wi * WSZ - PADK + pr, gc = wj * WSZ - PADK + pc;
    bool inb = (gr >= 0 && gr < HH && gc >= 0 && gc < WW);
    const float* xbq = lnx + (size_t)((inb ? gr : 0) * WW + (inb ? gc : 0)) * 128 + C2K;
    float qv[16];
#pragma unroll
    for (int d = 0; d < 16; d++) qv[d] = 0.f;
    if (inb) {
        const float4* xp = (const float4*)xbq;
#pragma unroll 4
        for (int c4 = 0; c4 < 16; c4++) {
            float4 x4 = xp[c4];
            axpy16(qv, x4.x, q2s[c4 * 4 + 0]);
            axpy16(qv, x4.y, q2s[c4 * 4 + 1]);
            axpy16(qv, x4.z, q2s[c4 * 4 + 2]);
            axpy16(qv, x4.w, q2s[c4 * 4 + 3]);
        }
    }
#pragma unroll
    for (int d = 0; d < 16; d++) qv[d] *= SCALE_F;
    __syncthreads();

    float m = -1e30f, l = 0.f, acc[16];
#pragma unroll
    for (int d = 0; d < 16; d++) acc[d] = 0.f;
    const float* bp = biasT + ((size_t)h * NQ1) * NKV1 + q;
    for (int n0 = 0; n0 < NQ1; n0 += 8) {
        float s[8];
#pragma unroll
        for (int j = 0; j < 8; j++) s[j] = bp[(size_t)(n0 + j) * NKV1];
#pragma unroll
        for (int j = 0; j < 8; j++) s[j] += dot16(qv, Ks[n0 + j]);
        float cm = fmaxf(fmaxf(fmaxf(s[0], s[1]), fmaxf(s[2], s[3])),
                         fmaxf(fmaxf(s[4], s[5]), fmaxf(s[6], s[7])));
        float mn = fmaxf(m, cm);
        float corr = __expf(m - mn);
        m = mn;
        l *= corr;
#pragma unroll
        for (int d = 0; d < 16; d++) acc[d] *= corr;
#pragma unroll
        for (int j = 0; j < 8; j++) {
            float e = __expf(s[j] - mn);
            l += e;
            axpy16(acc, e, Vs[n0 + j]);
        }
    }

    float rl = 1.f / l;
    float* op = bb + ((size_t)win * NKV1 + q) * C2K + h * HD;
#pragma unroll
    for (int d = 0; d < 16; d++) op[d] = acc[d] * rl + (inb ? xbq[h * HD + d] : 0.f);
}

// ---------------- fold (gather form, no atomics) ----------------
__global__ void fold_kernel(const float* __restrict__ bb, float* __restrict__ folded)
{
    int idx = blockIdx.x * 256 + threadIdx.x;
    if (idx >= 200 * 200 * 64) return;
    int c = idx & 63;
    int j = (idx >> 6) % 200;
    int i = idx / (64 * 200);
    int ilo = (i > 23) ? ((i - 8) >> 4) : 0;
    int ihi = min(11, i >> 4);
    int jlo = (j > 23) ? ((j - 8) >> 4) : 0;
    int jhi = min(11, j >> 4);
    float s = 0.f;
    for (int wi = ilo; wi <= ihi; wi++)
        for (int wj = jlo; wj <= jhi; wj++) {
            int p = (i - wi * 16) * OWSZ + (j - wj * 16);
            s += bb[((size_t)(wi * NWIN + wj) * NKV1 + p) * C2K + c];
        }
    folded[idx] = s;
}

// ---------------- bicubic resize 200->192 ----------------
__device__ __forceinline__ float cubicw(float x)
{
    float ax = fabsf(x);
    const float A = -0.75f;
    if (ax <= 1.f) return ((A + 2.f) * ax - (A + 3.f)) * ax * ax + 1.f;
    if (ax < 2.f)  return A * (ax * (ax * (ax - 5.f) + 8.f) - 4.f);
    return 0.f;
}

__global__ void resize_kernel(const float* __restrict__ folded, float* __restrict__ xcat)
{
    int idx = blockIdx.x * 256 + threadIdx.x;
    if (idx >= HH * WW * C2K) return;
    int c = idx & 63;
    int p = (idx >> 6) % WW;
    int o = idx / (C2K * WW);
    const float ratio = 200.f / 192.f;
    float sr = (o + 0.5f) * ratio - 0.5f;
    float sc = (p + 0.5f) * ratio - 0.5f;
    int fr = (int)floorf(sr), fcc = (int)floorf(sc);
    float wc[4]; int ic[4];
#pragma unroll
    for (int u = 0; u < 4; u++) {
        int jj = fcc - 1 + u;
        wc[u] = cubicw(sc - (float)jj);
        ic[u] = min(max(jj, 0), 199);
    }
    float acc = 0.f;
#pragma unroll
    for (int t = 0; t < 4; t++) {
        int ii = fr - 1 + t;
        float wr = cubicw(sr - (float)ii);
        int ir = min(max(ii, 0), 199);
        const float* rowp = folded + ((size_t)ir * 200) * 64 + c;
        float rs = 0.f;
#pragma unroll
        for (int u = 0; u < 4; u++) rs += wc[u] * rowp[(size_t)ic[u] * 64];
        acc += wr * rs;
    }
    xcat[(size_t)(o * WW + p) * 128 + C2K + c] = acc;
}

// ---------------- GEMM: C = (A1 [*A2]) @ B + bias [+ R], K = 128 ----------------
// 64(M) x 64(N) tile, 4x4 micro-tile per thread, f32 LDS, swizzled A.
__launch_bounds__(256)
__global__ void gemm_kernel(const float* __restrict__ A1, int a1s,
                            const float* __restrict__ A2, int a2s,
                            const float* __restrict__ B, int N,
                            const float* __restrict__ bias,
                            const float* __restrict__ R, int rs,
                            float* __restrict__ C, int cs)
{
    __shared__ float As[64][128];   // As[r][k ^ ((r&3)<<2)]
    __shared__ float Bs[128][64];
    int row0 = blockIdx.x * 64;
    int tid = threadIdx.x;
    int tc = tid & 15, tr = tid >> 4;

    for (int i = tid; i < 64 * 128; i += 256) {
        int r = i >> 7, k = i & 127;
        float v = A1[(size_t)(row0 + r) * a1s + k];
        if (A2) v *= A2[(size_t)(row0 + r) * a2s + k];
        As[r][k ^ ((r & 3) << 2)] = v;
    }

    for (int n0 = 0; n0 < N; n0 += 64) {
        __syncthreads();
        for (int i = tid; i < 128 * 64; i += 256) {
            int k = i >> 6, nn = i & 63;
            Bs[k][nn] = B[(size_t)k * N + n0 + nn];
        }
        __syncthreads();
        float creg[4][4];
#pragma unroll
        for (int i = 0; i < 4; i++)
#pragma unroll
            for (int j = 0; j < 4; j++) creg[i][j] = 0.f;
        for (int k = 0; k < 128; k++) {
            float4 b4 = *(const float4*)&Bs[k][tc * 4];
            float a0 = As[tr * 4 + 0][k ^ 0];
            float a1 = As[tr * 4 + 1][k ^ 4];
            float a2 = As[tr * 4 + 2][k ^ 8];
            float a3 = As[tr * 4 + 3][k ^ 12];
            creg[0][0] += a0 * b4.x; creg[0][1] += a0 * b4.y; creg[0][2] += a0 * b4.z; creg[0][3] += a0 * b4.w;
            creg[1][0] += a1 * b4.x; creg[1][1] += a1 * b4.y; creg[1][2] += a1 * b4.z; creg[1][3] += a1 * b4.w;
            creg[2][0] += a2 * b4.x; creg[2][1] += a2 * b4.y; creg[2][2] += a2 * b4.z; creg[2][3] += a2 * b4.w;
            creg[3][0] += a3 * b4.x; creg[3][1] += a3 * b4.y; creg[3][2] += a3 * b4.z; creg[3][3] += a3 * b4.w;
        }
#pragma unroll
        for (int i = 0; i < 4; i++) {
            size_t orow = (size_t)(row0 + tr * 4 + i);
            int col = n0 + tc * 4;
#pragma unroll
            for (int j = 0; j < 4; j++) {
                float acc = creg[i][j] + bias[col + j];
                if (R) acc += R[orow * rs + col + j];
                C[orow * cs + col + j] = acc;
            }
        }
    }
}

// ---------------- depthwise 3x3 conv ----------------
__global__ void dwconv_kernel(const float* __restrict__ x2n,  // h1 + 128, stride 256
                              const float* __restrict__ conv_w,
                              const float* __restrict__ conv_b,
                              float* __restrict__ x2c)
{
    int idx = blockIdx.x * 256 + threadIdx.x;
    if (idx >= NTOK * 128) return;
    int ch = idx & 127, t = idx >> 7;
    int i = t / WW, j = t % WW;
    float acc = conv_b[ch];
#pragma unroll
    for (int a = 0; a < 3; a++) {
        int ii = i + a - 1;
        if (ii < 0 || ii >= HH) continue;
#pragma unroll
        for (int b = 0; b < 3; b++) {
            int jj = j + b - 1;
            if (jj < 0 || jj >= WW) continue;
            acc += conv_w[ch * 9 + a * 3 + b] * x2n[(size_t)(ii * WW + jj) * 256 + ch];
        }
    }
    x2c[(size_t)t * 128 + ch] = acc;
}

extern "C" void kernel_launch(void* const* d_in, const int* in_sizes, int n_in,
                              void* d_out, int out_size, void* d_ws, size_t ws_size,
                              hipStream_t stream)
{
    (void)in_sizes; (void)n_in; (void)out_size; (void)ws_size;
    const float* x_tkn  = (const float*)d_in[0];
    const float* ln1_w  = (const float*)d_in[1];
    const float* ln1_b  = (const float*)d_in[2];
    const float* q1_w   = (const float*)d_in[3];
    const float* kv1_w  = (const float*)d_in[4];
    const float* rpb1   = (const float*)d_in[5];
    const float* q2_w   = (const float*)d_in[6];
    const float* kv2_w  = (const float*)d_in[7];
    const float* rpb2   = (const float*)d_in[8];
    const float* proj_w = (const float*)d_in[9];
    const float* proj_b = (const float*)d_in[10];
    const float* ln2_w  = (const float*)d_in[11];
    const float* ln2_b  = (const float*)d_in[12];
    const float* fc1_w  = (const float*)d_in[13];
    const float* fc1_b  = (const float*)d_in[14];
    const float* sgn_w  = (const float*)d_in[15];
    const float* sgn_b  = (const float*)d_in[16];
    const float* conv_w = (const float*)d_in[17];
    const float* conv_b = (const float*)d_in[18];
    const float* fc2_w  = (const float*)d_in[19];
    const float* fc2_b  = (const float*)d_in[20];
    const int*   rpi    = (const int*)d_in[21];

    float* ws = (float*)d_ws;
    float* lnx   = ws;               // 4,718,592  (ln_x; later x_buf)
    float* xcat  = ws + 4718592;     // 4,718,592  (x_cat; later x2c)
    float* bbuf  = ws + 9437184;     // 5,308,416  (bb; later y)
    float* foldp = ws + 14745600;    // 2,560,000  (folded)
    float* h1    = ws + 17305600;    // 9,437,184  (bias1T+bias2T early; h1 late)
    float* bias1T = h1;              // 2,359,296
    float* bias2T = h1 + 2359296;    //   589,824
    float* out   = (float*)d_out;

    // 1. LN1
    ln_kernel<<<NTOK / 4, 256, 0, stream>>>(x_tkn, 128, 0, lnx, 128, 0, ln1_w, ln1_b, NTOK);
    // 2. bias transposes
    bias1_kernel<<<(H2K * NKV1 * NQ1) / 256, 256, 0, stream>>>(rpb1, rpi, bias1T);
    bias2_kernel<<<(H2K * NQ1 * NKV1) / 256, 256, 0, stream>>>(rpb2, rpi, bias2T);
    // 3. attn1 -> xcat[:, 0:64] (+xa residual)
    attn1_kernel<<<dim3(144, 4), 256, 0, stream>>>(lnx, q1_w, kv1_w, bias1T, xcat);
    // 4. attn2 -> bb (+xb_p residual)
    attn2_kernel<<<dim3(144, 4), 576, 0, stream>>>(lnx, q2_w, kv2_w, bias2T, bbuf);
    // 5. fold bb -> folded (200x200x64)
    fold_kernel<<<(200 * 200 * 64) / 256, 256, 0, stream>>>(bbuf, foldp);
    // 6. bicubic resize -> xcat[:, 64:128]
    resize_kernel<<<(HH * WW * C2K) / 256, 256, 0, stream>>>(foldp, xcat);
    // 7. proj: x_buf = xcat @ proj_w + proj_b + x_tkn   (x_buf aliases lnx)
    gemm_kernel<<<NTOK / 64, 256, 0, stream>>>(xcat, 128, nullptr, 0, proj_w, 128, proj_b,
                                               x_tkn, 128, lnx, 128);
    // 8. LN2: y = LN(x_buf)   (y aliases bbuf)
    ln_kernel<<<NTOK / 4, 256, 0, stream>>>(lnx, 128, 0, bbuf, 128, 0, ln2_w, ln2_b, NTOK);
    // 9. fc1: h1 = y @ fc1_w + fc1_b  (N=256)
    gemm_kernel<<<NTOK / 64, 256, 0, stream>>>(bbuf, 128, nullptr, 0, fc1_w, 256, fc1_b,
                                               nullptr, 0, h1, 256);
    // 10. sgn LN on x2 half of h1 (in place)
    ln_kernel<<<NTOK / 4, 256, 0, stream>>>(h1, 256, 128, h1, 256, 128, sgn_w, sgn_b, NTOK);
    // 11. depthwise conv: x2c = dwconv(x2n)   (x2c aliases xcat)
    dwconv_kernel<<<(NTOK * 128) / 256, 256, 0, stream>>>(h1 + 128, conv_w, conv_b, xcat);
    // 12. fc2: out = (x1 * x2c) @ fc2_w + fc2_b + x_buf
    gemm_kernel<<<NTOK / 64, 256, 0, stream>>>(h1, 256, xcat, 128, fc2_w, 128, fc2_b,
                                               lnx, 128, out, 128);
}